// Round 3
// baseline (292.390 us; speedup 1.0000x reference)
//
#include <hip/hip_runtime.h>

typedef unsigned short u16;
typedef unsigned int u32;
typedef __bf16 bf16x8 __attribute__((ext_vector_type(8)));
typedef float f32x4 __attribute__((ext_vector_type(4)));

#define EPS 1e-5f
#define SCALE 0.17677669529663687f   // 1/sqrt(32)

__device__ __forceinline__ u16 f2bf(float f) {
  u32 u = __builtin_bit_cast(u32, f);
  u32 r = (u + 0x7fffu + ((u >> 16) & 1u)) >> 16;
  return (u16)r;
}
__device__ __forceinline__ float bf2f(u16 v) {
  return __builtin_bit_cast(float, (u32)v << 16);
}
__device__ __forceinline__ u32 pack2(float a, float b) {
  return (u32)f2bf(a) | ((u32)f2bf(b) << 16);
}

__device__ __forceinline__ void gload16(const u16* g, u16* l) {
  __builtin_amdgcn_global_load_lds(
      (const __attribute__((address_space(1))) void*)g,
      (__attribute__((address_space(3))) void*)l, 16, 0, 0);
}

// ---------------- LN of msa -> bf16 [32768][256] ----------------
__global__ __launch_bounds__(256) void k_ln_msa(const float* __restrict__ x,
                                                const float* __restrict__ w,
                                                const float* __restrict__ b,
                                                u16* __restrict__ y) {
  int wid = threadIdx.x >> 6, lane = threadIdx.x & 63;
  long row = (long)blockIdx.x * 4 + wid;
  const float4 v = *reinterpret_cast<const float4*>(x + row * 256 + lane * 4);
  float s = v.x + v.y + v.z + v.w;
  float ss = v.x * v.x + v.y * v.y + v.z * v.z + v.w * v.w;
#pragma unroll
  for (int off = 1; off < 64; off <<= 1) {
    s += __shfl_xor(s, off);
    ss += __shfl_xor(ss, off);
  }
  float m = s * (1.0f / 256.0f);
  float var = ss * (1.0f / 256.0f) - m * m;
  float rs = rsqrtf(var + EPS);
  int c = lane * 4;
  u16 o0 = f2bf((v.x - m) * rs * w[c + 0] + b[c + 0]);
  u16 o1 = f2bf((v.y - m) * rs * w[c + 1] + b[c + 1]);
  u16 o2 = f2bf((v.z - m) * rs * w[c + 2] + b[c + 2]);
  u16 o3 = f2bf((v.w - m) * rs * w[c + 3] + b[c + 3]);
  uint2 pk;
  pk.x = (u32)o0 | ((u32)o1 << 16);
  pk.y = (u32)o2 | ((u32)o3 << 16);
  *reinterpret_cast<uint2*>(y + row * 256 + c) = pk;
}

// ---------------- pair LN + @Wpair -> biasT[8][j=256][i=256] f32 ----------------
__global__ __launch_bounds__(256) void k_pair_bias(const float* __restrict__ x,
                                                   const float* __restrict__ w,
                                                   const float* __restrict__ b,
                                                   const float* __restrict__ Wp,
                                                   float* __restrict__ biasT) {
  int wid = threadIdx.x >> 6, lane = threadIdx.x & 63;
  long row = (long)blockIdx.x * 4 + wid;   // row = i*256 + j
  const float2 v = *reinterpret_cast<const float2*>(x + row * 128 + lane * 2);
  float s = v.x + v.y, ss = v.x * v.x + v.y * v.y;
#pragma unroll
  for (int off = 1; off < 64; off <<= 1) {
    s += __shfl_xor(s, off);
    ss += __shfl_xor(ss, off);
  }
  float m = s * (1.0f / 128.0f);
  float var = ss * (1.0f / 128.0f) - m * m;
  float rs = rsqrtf(var + EPS);
  int c = lane * 2;
  float x0 = (v.x - m) * rs * w[c] + b[c];
  float x1 = (v.y - m) * rs * w[c + 1] + b[c + 1];
  const float4* wp = reinterpret_cast<const float4*>(Wp + (long)c * 8);
  float4 a0 = wp[0], a1 = wp[1], a2 = wp[2], a3 = wp[3];
  float p[8];
  p[0] = x0 * a0.x + x1 * a2.x; p[1] = x0 * a0.y + x1 * a2.y;
  p[2] = x0 * a0.z + x1 * a2.z; p[3] = x0 * a0.w + x1 * a2.w;
  p[4] = x0 * a1.x + x1 * a3.x; p[5] = x0 * a1.y + x1 * a3.y;
  p[6] = x0 * a1.z + x1 * a3.z; p[7] = x0 * a1.w + x1 * a3.w;
#pragma unroll
  for (int off = 1; off < 64; off <<= 1) {
#pragma unroll
    for (int h = 0; h < 8; h++) p[h] += __shfl_xor(p[h], off);
  }
  if (lane == 0) {
    int i = (int)(row >> 8), j = (int)(row & 255);
#pragma unroll
    for (int h = 0; h < 8; h++) biasT[(long)h * 65536 + j * 256 + i] = p[h];
  }
}

// ---------------- transpose weights to bf16 ----------------
__global__ __launch_bounds__(256) void k_prep_w(const float* __restrict__ Wq,
                                                const float* __restrict__ Wk,
                                                const float* __restrict__ Wv,
                                                const float* __restrict__ Wg,
                                                const float* __restrict__ Wo,
                                                u16* __restrict__ Wt,
                                                u16* __restrict__ WoT) {
  int tid = blockIdx.x * 256 + threadIdx.x;
  if (tid < 262144) {
    int n = tid >> 8, kk = tid & 255;
    int sel = n >> 8, c = n & 255;
    const float* W = (sel == 0) ? Wq : (sel == 1) ? Wk : (sel == 2) ? Wv : Wg;
    Wt[tid] = f2bf(W[kk * 256 + c]);
  } else {
    int t = tid - 262144;
    int n = t >> 8, kk = t & 255;
    WoT[t] = f2bf(Wo[kk * 256 + n]);
  }
}

// ---------------- projection GEMM (128x128 tile, BK=32, dbuf LDS) ----------------
// msa_ln[32768,256] @ Wt^T ; epilogue writes head-major layouts:
//   qkg[t][h][row][32] for t=0(q*SCALE),1(k),2(sigmoid g) ; vt[s][h][32][256] = V^T
__global__ __launch_bounds__(256) void k_proj(const u16* __restrict__ X,
                                              const u16* __restrict__ Wt,
                                              const float* __restrict__ bg,
                                              u16* __restrict__ qkg,
                                              u16* __restrict__ vt) {
  __shared__ u16 As[2][4096];
  __shared__ u16 Bs[2][4096];
  int tid = threadIdx.x;
  int wid = tid >> 6, lane = tid & 63;
  int lr = lane & 15, lg = lane >> 4;
  int wr = wid >> 1, wc = wid & 1;
  int m0 = blockIdx.x * 128;
  int n0 = blockIdx.y * 128;
  int sel = n0 >> 8;  // uniform per block: 0=q 1=k 2=v 3=g

  int tr = tid >> 2, tc = (tid & 3) * 8;
  const u16* gA0 = X + (long)(m0 + tr) * 256 + tc;
  const u16* gA1 = X + (long)(m0 + 64 + tr) * 256 + tc;
  const u16* gB0 = Wt + (long)(n0 + tr) * 256 + tc;
  const u16* gB1 = Wt + (long)(n0 + 64 + tr) * 256 + tc;

  f32x4 acc[4][4];
#pragma unroll
  for (int mi = 0; mi < 4; mi++)
#pragma unroll
    for (int ni = 0; ni < 4; ni++) acc[mi][ni] = (f32x4){0.f, 0.f, 0.f, 0.f};

#define STAGE(buf, k0)                                  \
  do {                                                  \
    gload16(gA0 + (k0), &As[buf][tid * 8]);             \
    gload16(gA1 + (k0), &As[buf][2048 + tid * 8]);      \
    gload16(gB0 + (k0), &Bs[buf][tid * 8]);             \
    gload16(gB1 + (k0), &Bs[buf][2048 + tid * 8]);      \
  } while (0)

  STAGE(0, 0);
  __syncthreads();
#pragma unroll
  for (int step = 0; step < 8; step++) {
    int buf = step & 1;
    if (step < 7) STAGE(buf ^ 1, (step + 1) * 32);
    bf16x8 a[4], b[4];
#pragma unroll
    for (int mi = 0; mi < 4; mi++)
      a[mi] = *reinterpret_cast<const bf16x8*>(&As[buf][(wr * 64 + mi * 16 + lr) * 32 + lg * 8]);
#pragma unroll
    for (int ni = 0; ni < 4; ni++)
      b[ni] = *reinterpret_cast<const bf16x8*>(&Bs[buf][(wc * 64 + ni * 16 + lr) * 32 + lg * 8]);
#pragma unroll
    for (int mi = 0; mi < 4; mi++)
#pragma unroll
      for (int ni = 0; ni < 4; ni++)
        acc[mi][ni] = __builtin_amdgcn_mfma_f32_16x16x32_bf16(a[mi], b[ni], acc[mi][ni], 0, 0, 0);
    __syncthreads();
  }
#undef STAGE

  int s = m0 >> 8;  // uniform per block
#pragma unroll
  for (int ni = 0; ni < 4; ni++) {
    int col = n0 + wc * 64 + ni * 16 + lr;
    int cq = col & 255;
    int hh = cq >> 5, dd = cq & 31;
    if (sel == 2) {
      // V^T: pack 4 consecutive rows (i) into one 8B store
      u16* vbase = vt + (((long)s * 8 + hh) * 32 + dd) * 256;
#pragma unroll
      for (int mi = 0; mi < 4; mi++) {
        int i = (m0 & 255) + wr * 64 + mi * 16 + lg * 4;
        uint2 pk;
        pk.x = pack2(acc[mi][ni][0], acc[mi][ni][1]);
        pk.y = pack2(acc[mi][ni][2], acc[mi][ni][3]);
        *reinterpret_cast<uint2*>(vbase + i) = pk;
      }
    } else {
      int t = (sel == 3) ? 2 : sel;
      float bgv = (sel == 3) ? bg[cq] : 0.f;
      u16* qbase = qkg + ((long)(t * 8 + hh) * 32768) * 32;
#pragma unroll
      for (int mi = 0; mi < 4; mi++) {
#pragma unroll
        for (int r = 0; r < 4; r++) {
          int row = m0 + wr * 64 + mi * 16 + lg * 4 + r;
          float val = acc[mi][ni][r];
          if (sel == 0) val *= SCALE;
          else if (sel == 3) val = 1.0f / (1.0f + __expf(-(val + bgv)));
          qbase[(long)row * 32 + dd] = f2bf(val);
        }
      }
    }
  }
}

// ---------------- attention: one block per (s,h), 4 waves x 64 q-rows ----------------
__global__ __launch_bounds__(256) void k_attn(const u16* __restrict__ qkg,
                                              const u16* __restrict__ vt,
                                              const float* __restrict__ biasT,
                                              u16* __restrict__ vals) {
  __shared__ alignas(16) u16 Ks[256 * 40];    // K [j][d] rows padded to 40 elems
  __shared__ alignas(16) u16 VTs[32 * 264];   // V^T [d][j] rows padded to 264
  int tid = threadIdx.x;
  int wid = tid >> 6, lane = tid & 63;
  int lr = lane & 15, lg = lane >> 4;
  int h = blockIdx.x, s = blockIdx.y;

  const u16* qb = qkg + ((long)(0 + h) * 32768 + s * 256) * 32;
  const u16* kb = qkg + ((long)(8 + h) * 32768 + s * 256) * 32;
  const u16* gb = qkg + ((long)(16 + h) * 32768 + s * 256) * 32;
  const u16* vb = vt + ((long)s * 8 + h) * 32 * 256;

  // stage K -> Ks[j][40]
#pragma unroll
  for (int k = 0; k < 4; k++) {
    int c = tid + k * 256;
    uint4 u = *reinterpret_cast<const uint4*>(kb + c * 8);
    int j = c >> 2, p = c & 3;
    *reinterpret_cast<uint4*>(&Ks[j * 40 + p * 8]) = u;
  }
  // stage V^T -> VTs[d][264]
#pragma unroll
  for (int k = 0; k < 4; k++) {
    int c = tid + k * 256;
    uint4 u = *reinterpret_cast<const uint4*>(vb + c * 8);
    int d = c >> 5, p = c & 31;
    *reinterpret_cast<uint4*>(&VTs[d * 264 + p * 8]) = u;
  }
  __syncthreads();

  const float* bh = biasT + (long)h * 65536;

  for (int ig = 0; ig < 4; ig++) {
    int i0 = wid * 64 + ig * 16;
    bf16x8 qf = *reinterpret_cast<const bf16x8*>(qb + (i0 + lr) * 32 + lg * 8);

    // S^T tiles: p[jt] = C[j=jt*16+lg*4+r][i=i0+lr]
    f32x4 p[16];
#pragma unroll
    for (int jt = 0; jt < 16; jt++) {
      bf16x8 kf = *reinterpret_cast<const bf16x8*>(&Ks[(jt * 16 + lr) * 40 + lg * 8]);
      f32x4 z = (f32x4){0.f, 0.f, 0.f, 0.f};
      p[jt] = __builtin_amdgcn_mfma_f32_16x16x32_bf16(kf, qf, z, 0, 0, 0);
    }

    // + bias^T, column (=q-row) max over j
    float mx = -1e30f;
#pragma unroll
    for (int jt = 0; jt < 16; jt++) {
#pragma unroll
      for (int r = 0; r < 4; r++) {
        float v = p[jt][r] + bh[(jt * 16 + lg * 4 + r) * 256 + i0 + lr];
        p[jt][r] = v;
        mx = fmaxf(mx, v);
      }
    }
    mx = fmaxf(mx, __shfl_xor(mx, 16));
    mx = fmaxf(mx, __shfl_xor(mx, 32));

    float sum = 0.f;
    u32 pkA[16], pkB[16];
#pragma unroll
    for (int jt = 0; jt < 16; jt++) {
      float e0 = __expf(p[jt][0] - mx);
      float e1 = __expf(p[jt][1] - mx);
      float e2 = __expf(p[jt][2] - mx);
      float e3 = __expf(p[jt][3] - mx);
      sum += (e0 + e1) + (e2 + e3);
      pkA[jt] = pack2(e0, e1);
      pkB[jt] = pack2(e2, e3);
    }
    sum += __shfl_xor(sum, 16);
    sum += __shfl_xor(sum, 32);

    // PV: assemble P A-fragments via same-column lane exchange
    f32x4 o[2];
    o[0] = (f32x4){0.f, 0.f, 0.f, 0.f};
    o[1] = (f32x4){0.f, 0.f, 0.f, 0.f};
    int srcA = ((lg & 1) * 2) * 16 + lr;
    int srcB = srcA + 16;
    bool hi = lg >= 2;
#pragma unroll
    for (int ks = 0; ks < 8; ks++) {
      u32 aLo = (u32)__shfl((int)pkA[2 * ks], srcA);
      u32 aHi = (u32)__shfl((int)pkA[2 * ks + 1], srcA);
      u32 bLo = (u32)__shfl((int)pkB[2 * ks], srcA);
      u32 bHi = (u32)__shfl((int)pkB[2 * ks + 1], srcA);
      u32 cLo = (u32)__shfl((int)pkA[2 * ks], srcB);
      u32 cHi = (u32)__shfl((int)pkA[2 * ks + 1], srcB);
      u32 dLo = (u32)__shfl((int)pkB[2 * ks], srcB);
      u32 dHi = (u32)__shfl((int)pkB[2 * ks + 1], srcB);
      uint4 pu;
      pu.x = hi ? aHi : aLo;
      pu.y = hi ? bHi : bLo;
      pu.z = hi ? cHi : cLo;
      pu.w = hi ? dHi : dLo;
      bf16x8 pa = __builtin_bit_cast(bf16x8, pu);
#pragma unroll
      for (int nt = 0; nt < 2; nt++) {
        bf16x8 vf = *reinterpret_cast<const bf16x8*>(&VTs[(nt * 16 + lr) * 264 + ks * 32 + lg * 8]);
        o[nt] = __builtin_amdgcn_mfma_f32_16x16x32_bf16(pa, vf, o[nt], 0, 0, 0);
      }
    }

    // epilogue: normalize (per output row), gate, store
    float inv = 1.0f / sum;  // this lane holds sum for row i0+lr
#pragma unroll
    for (int r = 0; r < 4; r++) {
      float invr = __shfl(inv, lg * 4 + r);
      int row = i0 + lg * 4 + r;
#pragma unroll
      for (int nt = 0; nt < 2; nt++) {
        int d = nt * 16 + lr;
        float gv = bf2f(gb[(long)row * 32 + d]);
        float ov = o[nt][r] * invr * gv;
        vals[((long)s * 256 + row) * 256 + h * 32 + d] = f2bf(ov);
      }
    }
  }
}

// ---------------- out GEMM: vals[32768,256] @ Wo + bo -> f32 ----------------
__global__ __launch_bounds__(256) void k_out(const u16* __restrict__ X,
                                             const u16* __restrict__ WoT,
                                             const float* __restrict__ bo,
                                             float* __restrict__ out) {
  __shared__ u16 As[2][4096];
  __shared__ u16 Bs[2][4096];
  int tid = threadIdx.x;
  int wid = tid >> 6, lane = tid & 63;
  int lr = lane & 15, lg = lane >> 4;
  int wr = wid >> 1, wc = wid & 1;
  int m0 = blockIdx.x * 128;
  int n0 = blockIdx.y * 128;

  int tr = tid >> 2, tc = (tid & 3) * 8;
  const u16* gA0 = X + (long)(m0 + tr) * 256 + tc;
  const u16* gA1 = X + (long)(m0 + 64 + tr) * 256 + tc;
  const u16* gB0 = WoT + (long)(n0 + tr) * 256 + tc;
  const u16* gB1 = WoT + (long)(n0 + 64 + tr) * 256 + tc;

  f32x4 acc[4][4];
#pragma unroll
  for (int mi = 0; mi < 4; mi++)
#pragma unroll
    for (int ni = 0; ni < 4; ni++) acc[mi][ni] = (f32x4){0.f, 0.f, 0.f, 0.f};

#define STAGE(buf, k0)                                  \
  do {                                                  \
    gload16(gA0 + (k0), &As[buf][tid * 8]);             \
    gload16(gA1 + (k0), &As[buf][2048 + tid * 8]);      \
    gload16(gB0 + (k0), &Bs[buf][2048 + tid * 8 - 2048]); \
    gload16(gB1 + (k0), &Bs[buf][2048 + tid * 8]);      \
  } while (0)

  STAGE(0, 0);
  __syncthreads();
#pragma unroll
  for (int step = 0; step < 8; step++) {
    int buf = step & 1;
    if (step < 7) STAGE(buf ^ 1, (step + 1) * 32);
    bf16x8 a[4], b[4];
#pragma unroll
    for (int mi = 0; mi < 4; mi++)
      a[mi] = *reinterpret_cast<const bf16x8*>(&As[buf][(wr * 64 + mi * 16 + lr) * 32 + lg * 8]);
#pragma unroll
    for (int ni = 0; ni < 4; ni++)
      b[ni] = *reinterpret_cast<const bf16x8*>(&Bs[buf][(wc * 64 + ni * 16 + lr) * 32 + lg * 8]);
#pragma unroll
    for (int mi = 0; mi < 4; mi++)
#pragma unroll
      for (int ni = 0; ni < 4; ni++)
        acc[mi][ni] = __builtin_amdgcn_mfma_f32_16x16x32_bf16(a[mi], b[ni], acc[mi][ni], 0, 0, 0);
    __syncthreads();
  }
#undef STAGE

#pragma unroll
  for (int ni = 0; ni < 4; ni++) {
    int col = n0 + wc * 64 + ni * 16 + lr;
    float bias_c = bo[col];
#pragma unroll
    for (int mi = 0; mi < 4; mi++) {
#pragma unroll
      for (int r = 0; r < 4; r++) {
        int row = m0 + wr * 64 + mi * 16 + lg * 4 + r;
        out[(long)row * 256 + col] = acc[mi][ni][r] + bias_c;
      }
    }
  }
}

extern "C" void kernel_launch(void* const* d_in, const int* in_sizes, int n_in,
                              void* d_out, int out_size, void* d_ws, size_t ws_size,
                              hipStream_t stream) {
  (void)in_sizes; (void)n_in; (void)out_size; (void)ws_size;
  const float* msa = (const float*)d_in[0];
  const float* pair = (const float*)d_in[1];
  const float* ln_msa_w = (const float*)d_in[2];
  const float* ln_msa_b = (const float*)d_in[3];
  const float* ln_pair_w = (const float*)d_in[4];
  const float* ln_pair_b = (const float*)d_in[5];
  const float* Wq = (const float*)d_in[6];
  const float* Wk = (const float*)d_in[7];
  const float* Wv = (const float*)d_in[8];
  const float* Wpair = (const float*)d_in[9];
  const float* Wg = (const float*)d_in[10];
  const float* bg = (const float*)d_in[11];
  const float* Wo = (const float*)d_in[12];
  const float* bo = (const float*)d_in[13];
  float* out = (float*)d_out;

  char* ws = (char*)d_ws;
  u16* msa_ln = (u16*)(ws + 0);                    // 16,777,216 B
  u16* qkg    = (u16*)(ws + 16777216);             // 50,331,648 B  [3][8][32768][32]
  u16* vt     = (u16*)(ws + 67108864);             // 16,777,216 B  [128][8][32][256]
  float* biasT = (float*)(ws + 83886080);          //  2,097,152 B  [8][256][256]
  u16* vals   = (u16*)(ws + 85983232);             // 16,777,216 B
  u16* Wt     = (u16*)(ws + 102760448);            //    524,288 B
  u16* WoT    = (u16*)(ws + 103284736);            //    131,072 B

  k_prep_w<<<dim3(1280), dim3(256), 0, stream>>>(Wq, Wk, Wv, Wg, Wo, Wt, WoT);
  k_ln_msa<<<dim3(8192), dim3(256), 0, stream>>>(msa, ln_msa_w, ln_msa_b, msa_ln);
  k_pair_bias<<<dim3(16384), dim3(256), 0, stream>>>(pair, ln_pair_w, ln_pair_b, Wpair, biasT);
  k_proj<<<dim3(256, 8), dim3(256), 0, stream>>>(msa_ln, Wt, bg, qkg, vt);
  k_attn<<<dim3(8, 128), dim3(256), 0, stream>>>(qkg, vt, biasT, vals);
  k_out<<<dim3(256, 2), dim3(256), 0, stream>>>(vals, WoT, bo, out);
}

// Round 4
// 156.509 us; speedup vs baseline: 1.8682x; 1.8682x over previous
//
#include <hip/hip_runtime.h>

typedef unsigned short u16;
typedef unsigned int u32;
typedef __bf16 bf16x8 __attribute__((ext_vector_type(8)));
typedef float f32x4 __attribute__((ext_vector_type(4)));

#define EPS 1e-5f
#define SCALE 0.17677669529663687f   // 1/sqrt(32)

__device__ __forceinline__ u16 f2bf(float f) {
  u32 u = __builtin_bit_cast(u32, f);
  u32 r = (u + 0x7fffu + ((u >> 16) & 1u)) >> 16;
  return (u16)r;
}
__device__ __forceinline__ float bf2f(u16 v) {
  return __builtin_bit_cast(float, (u32)v << 16);
}
__device__ __forceinline__ u32 pack2(float a, float b) {
  return (u32)f2bf(a) | ((u32)f2bf(b) << 16);
}

__device__ __forceinline__ void gload16(const u16* g, u16* l) {
  __builtin_amdgcn_global_load_lds(
      (const __attribute__((address_space(1))) void*)g,
      (__attribute__((address_space(3))) void*)l, 16, 0, 0);
}

// ---------------- LN of msa -> bf16 [32768][256] ----------------
__global__ __launch_bounds__(256) void k_ln_msa(const float* __restrict__ x,
                                                const float* __restrict__ w,
                                                const float* __restrict__ b,
                                                u16* __restrict__ y) {
  int wid = threadIdx.x >> 6, lane = threadIdx.x & 63;
  long row = (long)blockIdx.x * 4 + wid;
  const float4 v = *reinterpret_cast<const float4*>(x + row * 256 + lane * 4);
  float s = v.x + v.y + v.z + v.w;
  float ss = v.x * v.x + v.y * v.y + v.z * v.z + v.w * v.w;
#pragma unroll
  for (int off = 1; off < 64; off <<= 1) {
    s += __shfl_xor(s, off);
    ss += __shfl_xor(ss, off);
  }
  float m = s * (1.0f / 256.0f);
  float var = ss * (1.0f / 256.0f) - m * m;
  float rs = rsqrtf(var + EPS);
  int c = lane * 4;
  u16 o0 = f2bf((v.x - m) * rs * w[c + 0] + b[c + 0]);
  u16 o1 = f2bf((v.y - m) * rs * w[c + 1] + b[c + 1]);
  u16 o2 = f2bf((v.z - m) * rs * w[c + 2] + b[c + 2]);
  u16 o3 = f2bf((v.w - m) * rs * w[c + 3] + b[c + 3]);
  uint2 pk;
  pk.x = (u32)o0 | ((u32)o1 << 16);
  pk.y = (u32)o2 | ((u32)o3 << 16);
  *reinterpret_cast<uint2*>(y + row * 256 + c) = pk;
}

// ---------------- pair LN + @Wpair -> biasT[8][j=256][i=256] f32 ----------------
__global__ __launch_bounds__(256) void k_pair_bias(const float* __restrict__ x,
                                                   const float* __restrict__ w,
                                                   const float* __restrict__ b,
                                                   const float* __restrict__ Wp,
                                                   float* __restrict__ biasT) {
  int wid = threadIdx.x >> 6, lane = threadIdx.x & 63;
  long row = (long)blockIdx.x * 4 + wid;   // row = i*256 + j
  const float2 v = *reinterpret_cast<const float2*>(x + row * 128 + lane * 2);
  float s = v.x + v.y, ss = v.x * v.x + v.y * v.y;
#pragma unroll
  for (int off = 1; off < 64; off <<= 1) {
    s += __shfl_xor(s, off);
    ss += __shfl_xor(ss, off);
  }
  float m = s * (1.0f / 128.0f);
  float var = ss * (1.0f / 128.0f) - m * m;
  float rs = rsqrtf(var + EPS);
  int c = lane * 2;
  float x0 = (v.x - m) * rs * w[c] + b[c];
  float x1 = (v.y - m) * rs * w[c + 1] + b[c + 1];
  const float4* wp = reinterpret_cast<const float4*>(Wp + (long)c * 8);
  float4 a0 = wp[0], a1 = wp[1], a2 = wp[2], a3 = wp[3];
  float p[8];
  p[0] = x0 * a0.x + x1 * a2.x; p[1] = x0 * a0.y + x1 * a2.y;
  p[2] = x0 * a0.z + x1 * a2.z; p[3] = x0 * a0.w + x1 * a2.w;
  p[4] = x0 * a1.x + x1 * a3.x; p[5] = x0 * a1.y + x1 * a3.y;
  p[6] = x0 * a1.z + x1 * a3.z; p[7] = x0 * a1.w + x1 * a3.w;
#pragma unroll
  for (int off = 1; off < 64; off <<= 1) {
#pragma unroll
    for (int h = 0; h < 8; h++) p[h] += __shfl_xor(p[h], off);
  }
  if (lane == 0) {
    int i = (int)(row >> 8), j = (int)(row & 255);
#pragma unroll
    for (int h = 0; h < 8; h++) biasT[(long)h * 65536 + j * 256 + i] = p[h];
  }
}

// ---------------- transpose weights to bf16 ----------------
__global__ __launch_bounds__(256) void k_prep_w(const float* __restrict__ Wq,
                                                const float* __restrict__ Wk,
                                                const float* __restrict__ Wv,
                                                const float* __restrict__ Wg,
                                                const float* __restrict__ Wo,
                                                u16* __restrict__ Wt,
                                                u16* __restrict__ WoT) {
  int tid = blockIdx.x * 256 + threadIdx.x;
  if (tid < 262144) {
    int n = tid >> 8, kk = tid & 255;
    int sel = n >> 8, c = n & 255;
    const float* W = (sel == 0) ? Wq : (sel == 1) ? Wk : (sel == 2) ? Wv : Wg;
    Wt[tid] = f2bf(W[kk * 256 + c]);
  } else {
    int t = tid - 262144;
    int n = t >> 8, kk = t & 255;
    WoT[t] = f2bf(Wo[kk * 256 + n]);
  }
}

// ---------------- projection GEMM (128x128 tile, BK=32, dbuf LDS) ----------------
// msa_ln[32768,256] @ Wt^T ; epilogue writes head-major layouts:
//   qkg[t][h][row][32] for t=0(q*SCALE),1(k),2(sigmoid g) ; vt[s][h][32][256] = V^T
__global__ __launch_bounds__(256) void k_proj(const u16* __restrict__ X,
                                              const u16* __restrict__ Wt,
                                              const float* __restrict__ bg,
                                              u16* __restrict__ qkg,
                                              u16* __restrict__ vt) {
  __shared__ u16 As[2][4096];
  __shared__ u16 Bs[2][4096];
  int tid = threadIdx.x;
  int wid = tid >> 6, lane = tid & 63;
  int lr = lane & 15, lg = lane >> 4;
  int wr = wid >> 1, wc = wid & 1;
  int m0 = blockIdx.x * 128;
  int n0 = blockIdx.y * 128;
  int sel = n0 >> 8;  // uniform per block: 0=q 1=k 2=v 3=g

  int tr = tid >> 2, tc = (tid & 3) * 8;
  const u16* gA0 = X + (long)(m0 + tr) * 256 + tc;
  const u16* gA1 = X + (long)(m0 + 64 + tr) * 256 + tc;
  const u16* gB0 = Wt + (long)(n0 + tr) * 256 + tc;
  const u16* gB1 = Wt + (long)(n0 + 64 + tr) * 256 + tc;

  f32x4 acc[4][4];
#pragma unroll
  for (int mi = 0; mi < 4; mi++)
#pragma unroll
    for (int ni = 0; ni < 4; ni++) acc[mi][ni] = (f32x4){0.f, 0.f, 0.f, 0.f};

#define STAGE(buf, k0)                                  \
  do {                                                  \
    gload16(gA0 + (k0), &As[buf][tid * 8]);             \
    gload16(gA1 + (k0), &As[buf][2048 + tid * 8]);      \
    gload16(gB0 + (k0), &Bs[buf][tid * 8]);             \
    gload16(gB1 + (k0), &Bs[buf][2048 + tid * 8]);      \
  } while (0)

  STAGE(0, 0);
  __syncthreads();
#pragma unroll
  for (int step = 0; step < 8; step++) {
    int buf = step & 1;
    if (step < 7) STAGE(buf ^ 1, (step + 1) * 32);
    bf16x8 a[4], b[4];
#pragma unroll
    for (int mi = 0; mi < 4; mi++)
      a[mi] = *reinterpret_cast<const bf16x8*>(&As[buf][(wr * 64 + mi * 16 + lr) * 32 + lg * 8]);
#pragma unroll
    for (int ni = 0; ni < 4; ni++)
      b[ni] = *reinterpret_cast<const bf16x8*>(&Bs[buf][(wc * 64 + ni * 16 + lr) * 32 + lg * 8]);
#pragma unroll
    for (int mi = 0; mi < 4; mi++)
#pragma unroll
      for (int ni = 0; ni < 4; ni++)
        acc[mi][ni] = __builtin_amdgcn_mfma_f32_16x16x32_bf16(a[mi], b[ni], acc[mi][ni], 0, 0, 0);
    __syncthreads();
  }
#undef STAGE

  int s = m0 >> 8;  // uniform per block
#pragma unroll
  for (int ni = 0; ni < 4; ni++) {
    int col = n0 + wc * 64 + ni * 16 + lr;
    int cq = col & 255;
    int hh = cq >> 5, dd = cq & 31;
    if (sel == 2) {
      // V^T: pack 4 consecutive rows (i) into one 8B store
      u16* vbase = vt + (((long)s * 8 + hh) * 32 + dd) * 256;
#pragma unroll
      for (int mi = 0; mi < 4; mi++) {
        int i = (m0 & 255) + wr * 64 + mi * 16 + lg * 4;
        uint2 pk;
        pk.x = pack2(acc[mi][ni][0], acc[mi][ni][1]);
        pk.y = pack2(acc[mi][ni][2], acc[mi][ni][3]);
        *reinterpret_cast<uint2*>(vbase + i) = pk;
      }
    } else {
      int t = (sel == 3) ? 2 : sel;
      float bgv = (sel == 3) ? bg[cq] : 0.f;
      u16* qbase = qkg + ((long)(t * 8 + hh) * 32768) * 32;
#pragma unroll
      for (int mi = 0; mi < 4; mi++) {
#pragma unroll
        for (int r = 0; r < 4; r++) {
          int row = m0 + wr * 64 + mi * 16 + lg * 4 + r;
          float val = acc[mi][ni][r];
          if (sel == 0) val *= SCALE;
          else if (sel == 3) val = 1.0f / (1.0f + __expf(-(val + bgv)));
          qbase[(long)row * 32 + dd] = f2bf(val);
        }
      }
    }
  }
}

// ---------------- attention: grid (4, 8, 128); wave = 16 q-rows ----------------
// swapped QK^T (S^T in regs) -> cheap softmax -> per-wave LDS transpose -> PV
__global__ __launch_bounds__(256) void k_attn(const u16* __restrict__ qkg,
                                              const u16* __restrict__ vt,
                                              const float* __restrict__ biasT,
                                              u16* __restrict__ vals) {
  __shared__ alignas(16) u16 VTs[32 * 272];        // V^T [d][j], stride 272
  __shared__ alignas(16) u16 Plds[4][16 * 272];    // per-wave P [i][j], stride 272
  int tid = threadIdx.x;
  int wid = tid >> 6, lane = tid & 63;
  int lr = lane & 15, lg = lane >> 4;
  int i0 = blockIdx.x * 64, h = blockIdx.y, s = blockIdx.z;

  const u16* qb = qkg + ((long)(0 + h) * 32768 + s * 256) * 32;
  const u16* kb = qkg + ((long)(8 + h) * 32768 + s * 256) * 32;
  const u16* gb = qkg + ((long)(16 + h) * 32768 + s * 256) * 32;
  const u16* vb = vt + ((long)s * 8 + h) * 32 * 256;

  // stage V^T -> VTs[d][272] (vectorized, no scatter)
#pragma unroll
  for (int k = 0; k < 4; k++) {
    int c = tid + k * 256;
    uint4 u = *reinterpret_cast<const uint4*>(vb + c * 8);
    int d = c >> 5, p = c & 31;
    *reinterpret_cast<uint4*>(&VTs[d * 272 + p * 8]) = u;
  }
  __syncthreads();

  int iw0 = i0 + wid * 16;
  bf16x8 qf = *reinterpret_cast<const bf16x8*>(qb + (long)(iw0 + lr) * 32 + lg * 8);

  // S^T tiles: p[jt][r] = S[j=jt*16+lg*4+r][i=iw0+lr]; K read from global (coalesced, L2-hot)
  f32x4 p[16];
#pragma unroll
  for (int jt = 0; jt < 16; jt++) {
    bf16x8 kf = *reinterpret_cast<const bf16x8*>(kb + (long)(jt * 16 + lr) * 32 + lg * 8);
    f32x4 z = (f32x4){0.f, 0.f, 0.f, 0.f};
    p[jt] = __builtin_amdgcn_mfma_f32_16x16x32_bf16(kf, qf, z, 0, 0, 0);
  }

  // + bias^T, per-column (q-row) max: reduction only across lg groups
  const float* bh = biasT + (long)h * 65536;
  float mx = -1e30f;
#pragma unroll
  for (int jt = 0; jt < 16; jt++) {
#pragma unroll
    for (int r = 0; r < 4; r++) {
      float v = p[jt][r] + bh[(jt * 16 + lg * 4 + r) * 256 + i0 + wid * 16 + lr];
      p[jt][r] = v;
      mx = fmaxf(mx, v);
    }
  }
  mx = fmaxf(mx, __shfl_xor(mx, 16));
  mx = fmaxf(mx, __shfl_xor(mx, 32));

  float sum = 0.f;
#pragma unroll
  for (int jt = 0; jt < 16; jt++) {
    float e0 = __expf(p[jt][0] - mx);
    float e1 = __expf(p[jt][1] - mx);
    float e2 = __expf(p[jt][2] - mx);
    float e3 = __expf(p[jt][3] - mx);
    sum += (e0 + e1) + (e2 + e3);
    // transpose via LDS: 4 j-consecutive bf16 -> one 8B write at P[i=lr][j=jt*16+lg*4]
    uint2 pk;
    pk.x = pack2(e0, e1);
    pk.y = pack2(e2, e3);
    *reinterpret_cast<uint2*>(&Plds[wid][lr * 272 + jt * 16 + lg * 4]) = pk;
  }
  sum += __shfl_xor(sum, 16);
  sum += __shfl_xor(sum, 32);

  // PV: A = P rows from per-wave LDS (wave-local, no barrier), B = V^T rows
  f32x4 o[2];
  o[0] = (f32x4){0.f, 0.f, 0.f, 0.f};
  o[1] = (f32x4){0.f, 0.f, 0.f, 0.f};
#pragma unroll
  for (int ks = 0; ks < 8; ks++) {
    bf16x8 pa = *reinterpret_cast<const bf16x8*>(&Plds[wid][lr * 272 + ks * 32 + lg * 8]);
#pragma unroll
    for (int nt = 0; nt < 2; nt++) {
      bf16x8 vf = *reinterpret_cast<const bf16x8*>(&VTs[(nt * 16 + lr) * 272 + ks * 32 + lg * 8]);
      o[nt] = __builtin_amdgcn_mfma_f32_16x16x32_bf16(pa, vf, o[nt], 0, 0, 0);
    }
  }

  // epilogue: normalize (per output row i = lg*4+r), gate, store
  float inv = 1.0f / sum;  // lane (lr,*) holds sum for row iw0+lr
#pragma unroll
  for (int r = 0; r < 4; r++) {
    float invr = __shfl(inv, lg * 4 + r);  // lane with lr == lg*4+r
    int row = iw0 + lg * 4 + r;
#pragma unroll
    for (int nt = 0; nt < 2; nt++) {
      int d = nt * 16 + lr;
      float gv = bf2f(gb[(long)row * 32 + d]);
      float ov = o[nt][r] * invr * gv;
      vals[((long)s * 256 + row) * 256 + h * 32 + d] = f2bf(ov);
    }
  }
}

// ---------------- out GEMM: vals[32768,256] @ Wo + bo -> f32 ----------------
__global__ __launch_bounds__(256) void k_out(const u16* __restrict__ X,
                                             const u16* __restrict__ WoT,
                                             const float* __restrict__ bo,
                                             float* __restrict__ out) {
  __shared__ u16 As[2][4096];
  __shared__ u16 Bs[2][4096];
  int tid = threadIdx.x;
  int wid = tid >> 6, lane = tid & 63;
  int lr = lane & 15, lg = lane >> 4;
  int wr = wid >> 1, wc = wid & 1;
  int m0 = blockIdx.x * 128;
  int n0 = blockIdx.y * 128;

  int tr = tid >> 2, tc = (tid & 3) * 8;
  const u16* gA0 = X + (long)(m0 + tr) * 256 + tc;
  const u16* gA1 = X + (long)(m0 + 64 + tr) * 256 + tc;
  const u16* gB0 = WoT + (long)(n0 + tr) * 256 + tc;
  const u16* gB1 = WoT + (long)(n0 + 64 + tr) * 256 + tc;

  f32x4 acc[4][4];
#pragma unroll
  for (int mi = 0; mi < 4; mi++)
#pragma unroll
    for (int ni = 0; ni < 4; ni++) acc[mi][ni] = (f32x4){0.f, 0.f, 0.f, 0.f};

#define STAGE(buf, k0)                                  \
  do {                                                  \
    gload16(gA0 + (k0), &As[buf][tid * 8]);             \
    gload16(gA1 + (k0), &As[buf][2048 + tid * 8]);      \
    gload16(gB0 + (k0), &Bs[buf][tid * 8]);             \
    gload16(gB1 + (k0), &Bs[buf][2048 + tid * 8]);      \
  } while (0)

  STAGE(0, 0);
  __syncthreads();
#pragma unroll
  for (int step = 0; step < 8; step++) {
    int buf = step & 1;
    if (step < 7) STAGE(buf ^ 1, (step + 1) * 32);
    bf16x8 a[4], b[4];
#pragma unroll
    for (int mi = 0; mi < 4; mi++)
      a[mi] = *reinterpret_cast<const bf16x8*>(&As[buf][(wr * 64 + mi * 16 + lr) * 32 + lg * 8]);
#pragma unroll
    for (int ni = 0; ni < 4; ni++)
      b[ni] = *reinterpret_cast<const bf16x8*>(&Bs[buf][(wc * 64 + ni * 16 + lr) * 32 + lg * 8]);
#pragma unroll
    for (int mi = 0; mi < 4; mi++)
#pragma unroll
      for (int ni = 0; ni < 4; ni++)
        acc[mi][ni] = __builtin_amdgcn_mfma_f32_16x16x32_bf16(a[mi], b[ni], acc[mi][ni], 0, 0, 0);
    __syncthreads();
  }
#undef STAGE

#pragma unroll
  for (int ni = 0; ni < 4; ni++) {
    int col = n0 + wc * 64 + ni * 16 + lr;
    float bias_c = bo[col];
#pragma unroll
    for (int mi = 0; mi < 4; mi++) {
#pragma unroll
      for (int r = 0; r < 4; r++) {
        int row = m0 + wr * 64 + mi * 16 + lg * 4 + r;
        out[(long)row * 256 + col] = acc[mi][ni][r] + bias_c;
      }
    }
  }
}

extern "C" void kernel_launch(void* const* d_in, const int* in_sizes, int n_in,
                              void* d_out, int out_size, void* d_ws, size_t ws_size,
                              hipStream_t stream) {
  (void)in_sizes; (void)n_in; (void)out_size; (void)ws_size;
  const float* msa = (const float*)d_in[0];
  const float* pair = (const float*)d_in[1];
  const float* ln_msa_w = (const float*)d_in[2];
  const float* ln_msa_b = (const float*)d_in[3];
  const float* ln_pair_w = (const float*)d_in[4];
  const float* ln_pair_b = (const float*)d_in[5];
  const float* Wq = (const float*)d_in[6];
  const float* Wk = (const float*)d_in[7];
  const float* Wv = (const float*)d_in[8];
  const float* Wpair = (const float*)d_in[9];
  const float* Wg = (const float*)d_in[10];
  const float* bg = (const float*)d_in[11];
  const float* Wo = (const float*)d_in[12];
  const float* bo = (const float*)d_in[13];
  float* out = (float*)d_out;

  char* ws = (char*)d_ws;
  u16* msa_ln = (u16*)(ws + 0);                    // 16,777,216 B
  u16* qkg    = (u16*)(ws + 16777216);             // 50,331,648 B  [3][8][32768][32]
  u16* vt     = (u16*)(ws + 67108864);             // 16,777,216 B  [128][8][32][256]
  float* biasT = (float*)(ws + 83886080);          //  2,097,152 B  [8][256][256]
  u16* vals   = (u16*)(ws + 85983232);             // 16,777,216 B
  u16* Wt     = (u16*)(ws + 102760448);            //    524,288 B
  u16* WoT    = (u16*)(ws + 103284736);            //    131,072 B

  k_prep_w<<<dim3(1280), dim3(256), 0, stream>>>(Wq, Wk, Wv, Wg, Wo, Wt, WoT);
  k_ln_msa<<<dim3(8192), dim3(256), 0, stream>>>(msa, ln_msa_w, ln_msa_b, msa_ln);
  k_pair_bias<<<dim3(16384), dim3(256), 0, stream>>>(pair, ln_pair_w, ln_pair_b, Wpair, biasT);
  k_proj<<<dim3(256, 8), dim3(256), 0, stream>>>(msa_ln, Wt, bg, qkg, vt);
  k_attn<<<dim3(4, 8, 128), dim3(256), 0, stream>>>(qkg, vt, biasT, vals);
  k_out<<<dim3(256, 2), dim3(256), 0, stream>>>(vals, WoT, bo, out);
}

// Round 5
// 152.286 us; speedup vs baseline: 1.9200x; 1.0277x over previous
//
#include <hip/hip_runtime.h>

typedef unsigned short u16;
typedef unsigned int u32;
typedef __bf16 bf16x8 __attribute__((ext_vector_type(8)));
typedef float f32x4 __attribute__((ext_vector_type(4)));

#define EPS 1e-5f
#define SCALE 0.17677669529663687f   // 1/sqrt(32)

__device__ __forceinline__ u16 f2bf(float f) {
  u32 u = __builtin_bit_cast(u32, f);
  u32 r = (u + 0x7fffu + ((u >> 16) & 1u)) >> 16;
  return (u16)r;
}
__device__ __forceinline__ float bf2f(u16 v) {
  return __builtin_bit_cast(float, (u32)v << 16);
}
__device__ __forceinline__ u32 pack2(float a, float b) {
  return (u32)f2bf(a) | ((u32)f2bf(b) << 16);
}

__device__ __forceinline__ void gload16(const u16* g, u16* l) {
  __builtin_amdgcn_global_load_lds(
      (const __attribute__((address_space(1))) void*)g,
      (__attribute__((address_space(3))) void*)l, 16, 0, 0);
}

// ---------------- LN of msa -> bf16 [32768][256] ----------------
__global__ __launch_bounds__(256) void k_ln_msa(const float* __restrict__ x,
                                                const float* __restrict__ w,
                                                const float* __restrict__ b,
                                                u16* __restrict__ y) {
  int wid = threadIdx.x >> 6, lane = threadIdx.x & 63;
  long row = (long)blockIdx.x * 4 + wid;
  const float4 v = *reinterpret_cast<const float4*>(x + row * 256 + lane * 4);
  float s = v.x + v.y + v.z + v.w;
  float ss = v.x * v.x + v.y * v.y + v.z * v.z + v.w * v.w;
#pragma unroll
  for (int off = 1; off < 64; off <<= 1) {
    s += __shfl_xor(s, off);
    ss += __shfl_xor(ss, off);
  }
  float m = s * (1.0f / 256.0f);
  float var = ss * (1.0f / 256.0f) - m * m;
  float rs = rsqrtf(var + EPS);
  int c = lane * 4;
  u16 o0 = f2bf((v.x - m) * rs * w[c + 0] + b[c + 0]);
  u16 o1 = f2bf((v.y - m) * rs * w[c + 1] + b[c + 1]);
  u16 o2 = f2bf((v.z - m) * rs * w[c + 2] + b[c + 2]);
  u16 o3 = f2bf((v.w - m) * rs * w[c + 3] + b[c + 3]);
  uint2 pk;
  pk.x = (u32)o0 | ((u32)o1 << 16);
  pk.y = (u32)o2 | ((u32)o3 << 16);
  *reinterpret_cast<uint2*>(y + row * 256 + c) = pk;
}

// ---------------- pair LN + @Wpair -> biasT[8][j=256][i=256] f32 ----------------
__global__ __launch_bounds__(256) void k_pair_bias(const float* __restrict__ x,
                                                   const float* __restrict__ w,
                                                   const float* __restrict__ b,
                                                   const float* __restrict__ Wp,
                                                   float* __restrict__ biasT) {
  int wid = threadIdx.x >> 6, lane = threadIdx.x & 63;
  long row = (long)blockIdx.x * 4 + wid;   // row = i*256 + j
  const float2 v = *reinterpret_cast<const float2*>(x + row * 128 + lane * 2);
  float s = v.x + v.y, ss = v.x * v.x + v.y * v.y;
#pragma unroll
  for (int off = 1; off < 64; off <<= 1) {
    s += __shfl_xor(s, off);
    ss += __shfl_xor(ss, off);
  }
  float m = s * (1.0f / 128.0f);
  float var = ss * (1.0f / 128.0f) - m * m;
  float rs = rsqrtf(var + EPS);
  int c = lane * 2;
  float x0 = (v.x - m) * rs * w[c] + b[c];
  float x1 = (v.y - m) * rs * w[c + 1] + b[c + 1];
  const float4* wp = reinterpret_cast<const float4*>(Wp + (long)c * 8);
  float4 a0 = wp[0], a1 = wp[1], a2 = wp[2], a3 = wp[3];
  float p[8];
  p[0] = x0 * a0.x + x1 * a2.x; p[1] = x0 * a0.y + x1 * a2.y;
  p[2] = x0 * a0.z + x1 * a2.z; p[3] = x0 * a0.w + x1 * a2.w;
  p[4] = x0 * a1.x + x1 * a3.x; p[5] = x0 * a1.y + x1 * a3.y;
  p[6] = x0 * a1.z + x1 * a3.z; p[7] = x0 * a1.w + x1 * a3.w;
#pragma unroll
  for (int off = 1; off < 64; off <<= 1) {
#pragma unroll
    for (int h = 0; h < 8; h++) p[h] += __shfl_xor(p[h], off);
  }
  if (lane == 0) {
    int i = (int)(row >> 8), j = (int)(row & 255);
#pragma unroll
    for (int h = 0; h < 8; h++) biasT[(long)h * 65536 + j * 256 + i] = p[h];
  }
}

// ---------------- transpose weights to bf16 (SCALE folded into Wq) ----------------
__global__ __launch_bounds__(256) void k_prep_w(const float* __restrict__ Wq,
                                                const float* __restrict__ Wk,
                                                const float* __restrict__ Wv,
                                                const float* __restrict__ Wg,
                                                const float* __restrict__ Wo,
                                                u16* __restrict__ Wt,
                                                u16* __restrict__ WoT) {
  int tid = blockIdx.x * 256 + threadIdx.x;
  if (tid < 262144) {
    int n = tid >> 8, kk = tid & 255;
    int sel = n >> 8, c = n & 255;
    const float* W = (sel == 0) ? Wq : (sel == 1) ? Wk : (sel == 2) ? Wv : Wg;
    float v = W[kk * 256 + c];
    if (sel == 0) v *= SCALE;
    Wt[tid] = f2bf(v);
  } else {
    int t = tid - 262144;
    int n = t >> 8, kk = t & 255;
    WoT[t] = f2bf(Wo[kk * 256 + n]);
  }
}

// ---------------- projection GEMM: 512 thr, tile 128M x 256N, BK=32, dbuf ----------------
// blockIdx.y = sel (0=q,1=k,2=v,3=g). Outputs head-major qkg / transposed vt.
__global__ __launch_bounds__(512) void k_proj(const u16* __restrict__ X,
                                              const u16* __restrict__ Wt,
                                              const float* __restrict__ bg,
                                              u16* __restrict__ qkg,
                                              u16* __restrict__ vt) {
  __shared__ u16 As[2][4096];   // [128][32]
  __shared__ u16 Bs[2][8192];   // [256][32]
  int tid = threadIdx.x;
  int wid = tid >> 6, lane = tid & 63;
  int lr = lane & 15, lg = lane >> 4;
  int wr = wid >> 2, wc = wid & 3;   // 2 x 4 waves
  int m0 = blockIdx.x * 128;
  int n0 = blockIdx.y * 256;
  int sel = blockIdx.y;

  int tr = tid >> 2, tc = (tid & 3) * 8;
  const u16* gA  = X  + (long)(m0 + tr) * 256 + tc;
  const u16* gB0 = Wt + (long)(n0 + tr) * 256 + tc;
  const u16* gB1 = Wt + (long)(n0 + 128 + tr) * 256 + tc;

  f32x4 acc[4][4];
#pragma unroll
  for (int mi = 0; mi < 4; mi++)
#pragma unroll
    for (int ni = 0; ni < 4; ni++) acc[mi][ni] = (f32x4){0.f, 0.f, 0.f, 0.f};

#define STAGE(buf, k0)                                  \
  do {                                                  \
    gload16(gA + (k0), &As[buf][tid * 8]);              \
    gload16(gB0 + (k0), &Bs[buf][tid * 8]);             \
    gload16(gB1 + (k0), &Bs[buf][4096 + tid * 8]);      \
  } while (0)

  STAGE(0, 0);
  __syncthreads();
#pragma unroll
  for (int step = 0; step < 8; step++) {
    int buf = step & 1;
    if (step < 7) STAGE(buf ^ 1, (step + 1) * 32);
    bf16x8 a[4], b[4];
#pragma unroll
    for (int mi = 0; mi < 4; mi++)
      a[mi] = *reinterpret_cast<const bf16x8*>(&As[buf][(wr * 64 + mi * 16 + lr) * 32 + lg * 8]);
#pragma unroll
    for (int ni = 0; ni < 4; ni++)
      b[ni] = *reinterpret_cast<const bf16x8*>(&Bs[buf][(wc * 64 + ni * 16 + lr) * 32 + lg * 8]);
#pragma unroll
    for (int mi = 0; mi < 4; mi++)
#pragma unroll
      for (int ni = 0; ni < 4; ni++)
        acc[mi][ni] = __builtin_amdgcn_mfma_f32_16x16x32_bf16(a[mi], b[ni], acc[mi][ni], 0, 0, 0);
    __syncthreads();
  }
#undef STAGE

  int s = m0 >> 8;
#pragma unroll
  for (int ni = 0; ni < 4; ni++) {
    int cq = wc * 64 + ni * 16 + lr;   // 0..255 within this matrix
    int hh = cq >> 5, dd = cq & 31;
    if (sel == 2) {
      u16* vbase = vt + (((long)s * 8 + hh) * 32 + dd) * 256;
#pragma unroll
      for (int mi = 0; mi < 4; mi++) {
        int i = (m0 & 255) + wr * 64 + mi * 16 + lg * 4;
        uint2 pk;
        pk.x = pack2(acc[mi][ni][0], acc[mi][ni][1]);
        pk.y = pack2(acc[mi][ni][2], acc[mi][ni][3]);
        *reinterpret_cast<uint2*>(vbase + i) = pk;
      }
    } else {
      int t = (sel == 3) ? 2 : sel;
      float bgv = (sel == 3) ? bg[cq] : 0.f;
      u16* qbase = qkg + ((long)(t * 8 + hh) * 32768) * 32;
#pragma unroll
      for (int mi = 0; mi < 4; mi++) {
#pragma unroll
        for (int r = 0; r < 4; r++) {
          int row = m0 + wr * 64 + mi * 16 + lg * 4 + r;
          float val = acc[mi][ni][r];
          if (sel == 3) val = 1.0f / (1.0f + __expf(-(val + bgv)));
          qbase[(long)row * 32 + dd] = f2bf(val);
        }
      }
    }
  }
}

// ---------------- attention: grid (4, 8, 128); wave = 16 q-rows ----------------
__global__ __launch_bounds__(256) void k_attn(const u16* __restrict__ qkg,
                                              const u16* __restrict__ vt,
                                              const float* __restrict__ biasT,
                                              u16* __restrict__ vals) {
  __shared__ alignas(16) u16 VTs[32 * 272];
  __shared__ alignas(16) u16 Plds[4][16 * 272];
  int tid = threadIdx.x;
  int wid = tid >> 6, lane = tid & 63;
  int lr = lane & 15, lg = lane >> 4;
  int i0 = blockIdx.x * 64, h = blockIdx.y, s = blockIdx.z;

  const u16* qb = qkg + ((long)(0 + h) * 32768 + s * 256) * 32;
  const u16* kb = qkg + ((long)(8 + h) * 32768 + s * 256) * 32;
  const u16* gb = qkg + ((long)(16 + h) * 32768 + s * 256) * 32;
  const u16* vb = vt + ((long)s * 8 + h) * 32 * 256;

#pragma unroll
  for (int k = 0; k < 4; k++) {
    int c = tid + k * 256;
    uint4 u = *reinterpret_cast<const uint4*>(vb + c * 8);
    int d = c >> 5, p = c & 31;
    *reinterpret_cast<uint4*>(&VTs[d * 272 + p * 8]) = u;
  }
  __syncthreads();

  int iw0 = i0 + wid * 16;
  bf16x8 qf = *reinterpret_cast<const bf16x8*>(qb + (long)(iw0 + lr) * 32 + lg * 8);

  f32x4 p[16];
#pragma unroll
  for (int jt = 0; jt < 16; jt++) {
    bf16x8 kf = *reinterpret_cast<const bf16x8*>(kb + (long)(jt * 16 + lr) * 32 + lg * 8);
    f32x4 z = (f32x4){0.f, 0.f, 0.f, 0.f};
    p[jt] = __builtin_amdgcn_mfma_f32_16x16x32_bf16(kf, qf, z, 0, 0, 0);
  }

  const float* bh = biasT + (long)h * 65536;
  float mx = -1e30f;
#pragma unroll
  for (int jt = 0; jt < 16; jt++) {
#pragma unroll
    for (int r = 0; r < 4; r++) {
      float v = p[jt][r] + bh[(jt * 16 + lg * 4 + r) * 256 + i0 + wid * 16 + lr];
      p[jt][r] = v;
      mx = fmaxf(mx, v);
    }
  }
  mx = fmaxf(mx, __shfl_xor(mx, 16));
  mx = fmaxf(mx, __shfl_xor(mx, 32));

  float sum = 0.f;
#pragma unroll
  for (int jt = 0; jt < 16; jt++) {
    float e0 = __expf(p[jt][0] - mx);
    float e1 = __expf(p[jt][1] - mx);
    float e2 = __expf(p[jt][2] - mx);
    float e3 = __expf(p[jt][3] - mx);
    sum += (e0 + e1) + (e2 + e3);
    uint2 pk;
    pk.x = pack2(e0, e1);
    pk.y = pack2(e2, e3);
    *reinterpret_cast<uint2*>(&Plds[wid][lr * 272 + jt * 16 + lg * 4]) = pk;
  }
  sum += __shfl_xor(sum, 16);
  sum += __shfl_xor(sum, 32);

  f32x4 o[2];
  o[0] = (f32x4){0.f, 0.f, 0.f, 0.f};
  o[1] = (f32x4){0.f, 0.f, 0.f, 0.f};
#pragma unroll
  for (int ks = 0; ks < 8; ks++) {
    bf16x8 pa = *reinterpret_cast<const bf16x8*>(&Plds[wid][lr * 272 + ks * 32 + lg * 8]);
#pragma unroll
    for (int nt = 0; nt < 2; nt++) {
      bf16x8 vf = *reinterpret_cast<const bf16x8*>(&VTs[(nt * 16 + lr) * 272 + ks * 32 + lg * 8]);
      o[nt] = __builtin_amdgcn_mfma_f32_16x16x32_bf16(pa, vf, o[nt], 0, 0, 0);
    }
  }

  float inv = 1.0f / sum;
#pragma unroll
  for (int r = 0; r < 4; r++) {
    float invr = __shfl(inv, lg * 4 + r);
    int row = iw0 + lg * 4 + r;
#pragma unroll
    for (int nt = 0; nt < 2; nt++) {
      int d = nt * 16 + lr;
      float gv = bf2f(gb[(long)row * 32 + d]);
      float ov = o[nt][r] * invr * gv;
      vals[((long)s * 256 + row) * 256 + h * 32 + d] = f2bf(ov);
    }
  }
}

// ---------------- out GEMM: 512 thr, tile 128M x 256N(full), BK=32 ----------------
__global__ __launch_bounds__(512) void k_out(const u16* __restrict__ X,
                                             const u16* __restrict__ WoT,
                                             const float* __restrict__ bo,
                                             float* __restrict__ out) {
  __shared__ u16 As[2][4096];
  __shared__ u16 Bs[2][8192];
  int tid = threadIdx.x;
  int wid = tid >> 6, lane = tid & 63;
  int lr = lane & 15, lg = lane >> 4;
  int wr = wid >> 2, wc = wid & 3;
  int m0 = blockIdx.x * 128;

  int tr = tid >> 2, tc = (tid & 3) * 8;
  const u16* gA  = X   + (long)(m0 + tr) * 256 + tc;
  const u16* gB0 = WoT + (long)tr * 256 + tc;
  const u16* gB1 = WoT + (long)(128 + tr) * 256 + tc;

  f32x4 acc[4][4];
#pragma unroll
  for (int mi = 0; mi < 4; mi++)
#pragma unroll
    for (int ni = 0; ni < 4; ni++) acc[mi][ni] = (f32x4){0.f, 0.f, 0.f, 0.f};

#define STAGE(buf, k0)                                  \
  do {                                                  \
    gload16(gA + (k0), &As[buf][tid * 8]);              \
    gload16(gB0 + (k0), &Bs[buf][tid * 8]);             \
    gload16(gB1 + (k0), &Bs[buf][4096 + tid * 8]);      \
  } while (0)

  STAGE(0, 0);
  __syncthreads();
#pragma unroll
  for (int step = 0; step < 8; step++) {
    int buf = step & 1;
    if (step < 7) STAGE(buf ^ 1, (step + 1) * 32);
    bf16x8 a[4], b[4];
#pragma unroll
    for (int mi = 0; mi < 4; mi++)
      a[mi] = *reinterpret_cast<const bf16x8*>(&As[buf][(wr * 64 + mi * 16 + lr) * 32 + lg * 8]);
#pragma unroll
    for (int ni = 0; ni < 4; ni++)
      b[ni] = *reinterpret_cast<const bf16x8*>(&Bs[buf][(wc * 64 + ni * 16 + lr) * 32 + lg * 8]);
#pragma unroll
    for (int mi = 0; mi < 4; mi++)
#pragma unroll
      for (int ni = 0; ni < 4; ni++)
        acc[mi][ni] = __builtin_amdgcn_mfma_f32_16x16x32_bf16(a[mi], b[ni], acc[mi][ni], 0, 0, 0);
    __syncthreads();
  }
#undef STAGE

#pragma unroll
  for (int ni = 0; ni < 4; ni++) {
    int col = wc * 64 + ni * 16 + lr;
    float bias_c = bo[col];
#pragma unroll
    for (int mi = 0; mi < 4; mi++) {
#pragma unroll
      for (int r = 0; r < 4; r++) {
        int row = m0 + wr * 64 + mi * 16 + lg * 4 + r;
        out[(long)row * 256 + col] = acc[mi][ni][r] + bias_c;
      }
    }
  }
}

extern "C" void kernel_launch(void* const* d_in, const int* in_sizes, int n_in,
                              void* d_out, int out_size, void* d_ws, size_t ws_size,
                              hipStream_t stream) {
  (void)in_sizes; (void)n_in; (void)out_size; (void)ws_size;
  const float* msa = (const float*)d_in[0];
  const float* pair = (const float*)d_in[1];
  const float* ln_msa_w = (const float*)d_in[2];
  const float* ln_msa_b = (const float*)d_in[3];
  const float* ln_pair_w = (const float*)d_in[4];
  const float* ln_pair_b = (const float*)d_in[5];
  const float* Wq = (const float*)d_in[6];
  const float* Wk = (const float*)d_in[7];
  const float* Wv = (const float*)d_in[8];
  const float* Wpair = (const float*)d_in[9];
  const float* Wg = (const float*)d_in[10];
  const float* bg = (const float*)d_in[11];
  const float* Wo = (const float*)d_in[12];
  const float* bo = (const float*)d_in[13];
  float* out = (float*)d_out;

  char* ws = (char*)d_ws;
  u16* msa_ln = (u16*)(ws + 0);                    // 16,777,216 B
  u16* qkg    = (u16*)(ws + 16777216);             // 50,331,648 B  [3][8][32768][32]
  u16* vt     = (u16*)(ws + 67108864);             // 16,777,216 B  [128][8][32][256]
  float* biasT = (float*)(ws + 83886080);          //  2,097,152 B  [8][256][256]
  u16* vals   = (u16*)(ws + 85983232);             // 16,777,216 B
  u16* Wt     = (u16*)(ws + 102760448);            //    524,288 B
  u16* WoT    = (u16*)(ws + 103284736);            //    131,072 B

  k_prep_w<<<dim3(1280), dim3(256), 0, stream>>>(Wq, Wk, Wv, Wg, Wo, Wt, WoT);
  k_ln_msa<<<dim3(8192), dim3(256), 0, stream>>>(msa, ln_msa_w, ln_msa_b, msa_ln);
  k_pair_bias<<<dim3(16384), dim3(256), 0, stream>>>(pair, ln_pair_w, ln_pair_b, Wpair, biasT);
  k_proj<<<dim3(256, 4), dim3(512), 0, stream>>>(msa_ln, Wt, bg, qkg, vt);
  k_attn<<<dim3(4, 8, 128), dim3(256), 0, stream>>>(qkg, vt, biasT, vals);
  k_out<<<dim3(256), dim3(512), 0, stream>>>(vals, WoT, bo, out);
}